// Round 13
// baseline (2379.427 us; speedup 1.0000x reference)
//
#include <hip/hip_runtime.h>
#include <hip/hip_bf16.h>
#include <stdint.h>

// ---------------- constants ----------------
#define N_NODES   20000
#define MPAD      20224          // 158*128 = 79*256
#define N_TYPES   5
#define N_EDGES   64000
#define IN_C      2048
#define HID_C     1024
#define OUT_C     512

typedef __attribute__((ext_vector_type(8))) short short8;     // 8 bf16 (4 VGPR)
typedef __attribute__((ext_vector_type(4))) float f32x4;
typedef __attribute__((ext_vector_type(16))) float f32x16;    // 32x32 MFMA acc

// ---------------- helpers ----------------
__device__ __forceinline__ unsigned short f2b(float f) {
  union { float f; uint32_t u; } c; c.f = f;
  uint32_t u = c.u;
  u += 0x7FFFu + ((u >> 16) & 1u);          // RNE
  return (unsigned short)(u >> 16);
}
__device__ __forceinline__ float b2f(unsigned short h) {
  union { uint32_t u; float f; } c; c.u = ((uint32_t)h) << 16; return c.f;
}
__device__ __forceinline__ void gload_lds16(const void* g, void* l) {
  __builtin_amdgcn_global_load_lds((__attribute__((address_space(1))) void*)g,
                                   (__attribute__((address_space(3))) void*)l,
                                   16, 0, 0);
}

// ---------------- small prep kernels ----------------
__global__ __launch_bounds__(64) void softmax5_k(const float* __restrict__ attn, float* __restrict__ w) {
  if (threadIdx.x == 0) {
    float m = attn[0];
    for (int i = 1; i < N_TYPES; ++i) m = fmaxf(m, attn[i]);
    float e[N_TYPES], s = 0.f;
    for (int i = 0; i < N_TYPES; ++i) { e[i] = expf(attn[i] - m); s += e[i]; }
    for (int i = 0; i < N_TYPES; ++i) w[i] = e[i] / s;
  }
}

__global__ __launch_bounds__(256) void zero_int_k(int* __restrict__ p, int n) {
  int i = blockIdx.x * 256 + threadIdx.x;
  if (i < n) p[i] = 0;
}

__global__ __launch_bounds__(256) void hist_k(const int* __restrict__ edges, int* __restrict__ deg) {
  int t = blockIdx.x * 256 + threadIdx.x;
  if (t < N_TYPES * N_EDGES) {
    int ty = t / N_EDGES, e = t - ty * N_EDGES;
    int dst = edges[ty * 2 * N_EDGES + N_EDGES + e];
    atomicAdd(&deg[ty * N_NODES + dst], 1);
  }
}

__global__ __launch_bounds__(256) void scan_k(const int* __restrict__ deg, int* __restrict__ rowptr,
                                              int* __restrict__ cursor) {
  int ty = blockIdx.x;
  const int* d = deg + ty * N_NODES;
  int* rp = rowptr + ty * (N_NODES + 1);
  int* cu = cursor + ty * N_NODES;
  __shared__ int sh[256];
  __shared__ int s_carry;
  int tid = threadIdx.x;
  if (tid == 0) s_carry = 0;
  __syncthreads();
  for (int base = 0; base < N_NODES; base += 256) {
    int i = base + tid;
    int v = (i < N_NODES) ? d[i] : 0;
    sh[tid] = v; __syncthreads();
    for (int off = 1; off < 256; off <<= 1) {
      int t2 = (tid >= off) ? sh[tid - off] : 0;
      __syncthreads();
      sh[tid] += t2;
      __syncthreads();
    }
    int incl = sh[tid];
    int c = s_carry;
    if (i < N_NODES) { rp[i] = c + incl - v; cu[i] = c + incl - v; }
    __syncthreads();
    if (tid == 255) s_carry = c + incl;
    __syncthreads();
  }
  if (tid == 0) rp[N_NODES] = s_carry;
}

__global__ __launch_bounds__(256) void scatter_k(const int* __restrict__ edges, int* __restrict__ cursor,
                                                 int* __restrict__ colidx) {
  int t = blockIdx.x * 256 + threadIdx.x;
  if (t < N_TYPES * N_EDGES) {
    int ty = t / N_EDGES, e = t - ty * N_EDGES;
    int src = edges[ty * 2 * N_EDGES + e];
    int dst = edges[ty * 2 * N_EDGES + N_EDGES + e];
    int pos = atomicAdd(&cursor[ty * N_NODES + dst], 1);
    colidx[ty * N_EDGES + pos] = src;
  }
}

// x fp32 [20000,2048] -> bf16 [20224,2048], pad rows zero
__global__ __launch_bounds__(256) void cvt_x_k(const float* __restrict__ x, unsigned short* __restrict__ xb) {
  int i = blockIdx.x * 256 + threadIdx.x;
  int row = i >> 9;
  int c4 = (i & 511) << 2;
  if (row >= MPAD) return;
  ushort4 o;
  if (row < N_NODES) {
    float4 v = *(const float4*)(x + (size_t)row * IN_C + c4);
    o.x = f2b(v.x); o.y = f2b(v.y); o.z = f2b(v.z); o.w = f2b(v.w);
  } else { o.x = 0; o.y = 0; o.z = 0; o.w = 0; }
  *(ushort4*)(xb + (size_t)row * IN_C + c4) = o;
}

// fp32 W [5][C][K] -> bf16 Wcat [5][2C][K], placed at row offset rowoff
__global__ __launch_bounds__(256) void cvt_wcat_k(const float* __restrict__ s,
                                                  unsigned short* __restrict__ d,
                                                  int C, int K4, int rowoff) {
  int i = blockIdx.x * 256 + threadIdx.x;
  int total = N_TYPES * C * K4;
  if (i >= total) return;
  int k4 = i % K4;
  int rr = (i / K4) % C;
  int it = i / (C * K4);
  float4 v = ((const float4*)s)[i];
  ushort4 o; o.x = f2b(v.x); o.y = f2b(v.y); o.z = f2b(v.z); o.w = f2b(v.w);
  ((ushort4*)d)[((size_t)it * 2 * C + rowoff + rr) * K4 + k4] = o;
}

// ---------------- GEMM: PQ[itl] = A[itl] @ Wcat[itl]^T  (128x256, ring-3, 2 blk/CU, 32x32 MFMA) --
// 8 waves (2Mx4N), per-wave 64x64 = 2x2 frags of 32x32, BK=32, mfma_f32_32x32x16_bf16.
// LDS: 3 ring slots x (A 8 regions + B 16 regions) x 1024B = 72 KiB -> 2 blocks/CU.
// Schedule = r12 (lookahead-2, steady vmcnt(3), one barrier/K32-tile, hoisted ds_reads).
// 32x32 CONTENT REMAP (r10's conflict fix): physical read pattern is byte-identical to the
// verified conflict-free r12 pattern (region*1024 + off(lane&15, lane>>4)); instead the
// STORAGE is permuted: region R=2b+ks holds tile-rows 32b + f + 16*(g&1), k-chunk
// (g>>1)+2ks at phys(f,g). Then lane l's read delivers row 32b+(l&31), chunk (l>>5)+2ks
// = exactly the 32x32 A/B operand. Staging keeps LDS dest linear; only the global SOURCE
// per-lane address changes (element-traced: phys(5,2) writer lane 20 / reader lane 37 ok).
// D layout: col=lane&31, row=(reg&3)+8*(reg>>2)+4*(lane>>5)  [m74/m101-verified].
template<int NSIZE, int KSIZE>
__global__ __launch_bounds__(512, 4) void gemm_k(
    const unsigned short* __restrict__ Abase, size_t aS,     // per-itl stride (0 = shared A)
    const unsigned short* __restrict__ Wbase,                // [itl][NSIZE][KSIZE] (group-offset)
    unsigned short* __restrict__ PQ) {                       // [itl][MPAD][NSIZE]
  constexpr int NT = KSIZE / 32;
  constexpr int MT = MPAD / 128;     // BM = 128
  constexpr int NB = NSIZE / 256;    // BN = 256
  __shared__ unsigned short As[3][4096];   // 8 regions x 1024 B
  __shared__ unsigned short Bs[3][8192];   // 16 regions x 1024 B
  const int tid = threadIdx.x;
  const int lane = tid & 63;
  const int wave = tid >> 6;
  const int wm = wave >> 2, wn = wave & 3;   // 2M x 4N, per-wave 64x64

  // XCD-chunked bijective swizzle (m204), column-fastest within type
  const int nwg = gridDim.x;
  const int flat = blockIdx.x;
  const int q8 = nwg >> 3, r8 = nwg & 7;
  const int xcd = flat & 7, idx = flat >> 3;
  const int wg = (xcd < r8) ? (xcd * (q8 + 1) + idx) : (r8 * (q8 + 1) + (xcd - r8) * q8 + idx);
  const int itl = wg / (MT * NB);
  const int rem = wg % (MT * NB);
  const int row0 = (rem / NB) * 128;
  const int col0 = (rem % NB) * 256;

  const unsigned short* A = Abase + (size_t)itl * aS;
  const unsigned short* W = Wbase + (size_t)itl * NSIZE * KSIZE;

  // staging lane constants: lane l writes phys(f,g) of its region
  const int su = (lane & 7) ^ ((lane >> 3) & 7);     // u' = slot6 ^ (j&7)
  const int sf = 2 * (lane >> 3) + (su >> 2);        // f = phys row-in-16
  const int sg = su & 3;                             // g = phys 16B chunk
  // content map: row = 32*(reg>>1) + f + 16*(g&1); k-chunk = (g>>1) + 2*(reg&1)
  const int srowoff = sf + 16 * (sg & 1);            // row offset within 32-row block
  const int sch = sg >> 1;                           // k-chunk low bit

  // fragment read: per-lane phys offset (identical function of lane as r12 -> 0 conflicts)
  const int fr = lane & 15, g4 = lane >> 4;
  const int aoffb = ((fr >> 1) << 7) + (((((fr & 1) << 2) | g4) ^ ((fr >> 1) & 7)) << 4);

  auto stageA = [&](int t) {           // 1 load/wave: region = wave (A regions 0..7)
    int s = t % 3; int kb = t * 32;
    int reg = wave;
    gload_lds16(A + (size_t)(row0 + 32 * (reg >> 1) + srowoff) * KSIZE
                  + kb + (sch + 2 * (reg & 1)) * 8,
                &As[s][reg * 512]);
  };
  auto stageB = [&](int t) {           // 2 loads/wave: regions wave, wave+8 (B regions 0..15)
    int s = t % 3; int kb = t * 32;
#pragma unroll
    for (int j = 0; j < 2; ++j) {
      int reg = wave + 8 * j;
      gload_lds16(W + (size_t)(col0 + 32 * (reg >> 1) + srowoff) * KSIZE
                    + kb + (sch + 2 * (reg & 1)) * 8,
                  &Bs[s][reg * 512]);
    }
  };

  f32x16 acc[2][2];
#pragma unroll
  for (int m2 = 0; m2 < 2; ++m2)
#pragma unroll
    for (int n2 = 0; n2 < 2; ++n2) acc[m2][n2] = (f32x16)(0.f);

  // prologue: tiles 0,1 staged (6 loads/wave in flight)
  stageA(0); stageB(0);
  stageA(1); stageB(1);

  for (int t = 0; t < NT; ++t) {
    if (t < NT - 1) asm volatile("s_waitcnt vmcnt(3)" ::: "memory");
    else            asm volatile("s_waitcnt vmcnt(0)" ::: "memory");
    __builtin_amdgcn_s_barrier();
    __builtin_amdgcn_sched_barrier(0);
    const int slot = t % 3;
    const char* pa = (const char*)As[slot];
    const char* pb = (const char*)Bs[slot];
    // cluster 1: A frags (regions wm*4 + m2*2 + ks) + B n2=0; stage A(t+2); 4 MFMA
    short8 av[2][2], bv0[2];
#pragma unroll
    for (int m2 = 0; m2 < 2; ++m2)
#pragma unroll
      for (int ks = 0; ks < 2; ++ks)
        av[m2][ks] = *(const short8*)(pa + ((wm * 4 + m2 * 2 + ks) << 10) + aoffb);
#pragma unroll
    for (int ks = 0; ks < 2; ++ks)
      bv0[ks] = *(const short8*)(pb + ((wn * 4 + ks) << 10) + aoffb);
    if (t + 2 < NT) stageA(t + 2);
    __builtin_amdgcn_s_setprio(1);
#pragma unroll
    for (int m2 = 0; m2 < 2; ++m2)
#pragma unroll
      for (int ks = 0; ks < 2; ++ks)
        acc[m2][0] = __builtin_amdgcn_mfma_f32_32x32x16_bf16(av[m2][ks], bv0[ks], acc[m2][0], 0, 0, 0);
    __builtin_amdgcn_s_setprio(0);
    // cluster 2: B n2=1; stage B(t+2); 4 MFMA
    short8 bv1[2];
#pragma unroll
    for (int ks = 0; ks < 2; ++ks)
      bv1[ks] = *(const short8*)(pb + ((wn * 4 + 2 + ks) << 10) + aoffb);
    if (t + 2 < NT) stageB(t + 2);
    __builtin_amdgcn_s_setprio(1);
#pragma unroll
    for (int m2 = 0; m2 < 2; ++m2)
#pragma unroll
      for (int ks = 0; ks < 2; ++ks)
        acc[m2][1] = __builtin_amdgcn_mfma_f32_32x32x16_bf16(av[m2][ks], bv1[ks], acc[m2][1], 0, 0, 0);
    __builtin_amdgcn_s_setprio(0);
  }

  // epilogue: 32x32 D layout col=lane&31, row=(reg&3)+8*(reg>>2)+4*(lane>>5)
  const int ecol = lane & 31;
  const int ebase = 4 * (lane >> 5);
  unsigned short* Op = PQ + (size_t)itl * MPAD * NSIZE;
#pragma unroll
  for (int m2 = 0; m2 < 2; ++m2) {
#pragma unroll
    for (int n2 = 0; n2 < 2; ++n2) {
      int gcol = col0 + (wn * 2 + n2) * 32 + ecol;
#pragma unroll
      for (int r = 0; r < 16; ++r) {
        int crow = (r & 3) + 8 * (r >> 2) + ebase;
        int grow = row0 + (wm * 2 + m2) * 32 + crow;
        Op[(size_t)grow * NSIZE + gcol] = f2b(acc[m2][n2][r]);
      }
    }
  }
}

// ---------------- combine L1/L2: h' = relu(mean_gather(P) + bl + Q); pad rows zeroed ----------------
// 16 B/lane (short8); 2 nodes per 256-thread block (128 lanes x 16B = full 1024-col row)
__global__ __launch_bounds__(256) void combine12_k(const unsigned short* __restrict__ PQ,
                                                   unsigned short* __restrict__ Hn,
                                                   const float* __restrict__ bl,
                                                   const int* __restrict__ rowptr,
                                                   const int* __restrict__ colidx, int it0) {
  constexpr int C = HID_C;
  constexpr int HP = MPAD / 2;
  int itl = blockIdx.x / HP;
  int pair = blockIdx.x % HP;
  int half = threadIdx.x >> 7;              // 0/1: which node of the pair
  int lane = threadIdx.x & 127;             // 128 lanes x 8 bf16 = 1024 cols
  int node = pair * 2 + half;
  int it = it0 + itl;
  short8* hp = (short8*)(Hn + ((size_t)itl * MPAD + node) * C + lane * 8);
  if (node >= N_NODES) { short8 z = (short8)0; *hp = z; return; }
  const unsigned short* Pb = PQ + (size_t)itl * MPAD * 2 * C;
  const int* rp = rowptr + (size_t)it * (N_NODES + 1);
  const int* ci = colidx + (size_t)it * N_EDGES;
  int beg = rp[node], end = rp[node + 1];
  float a[8];
#pragma unroll
  for (int j = 0; j < 8; ++j) a[j] = 0.f;
  for (int e = beg; e < end; ++e) {
    int src = ci[e];
    short8 u = *(const short8*)(Pb + (size_t)src * 2 * C + lane * 8);
#pragma unroll
    for (int j = 0; j < 8; ++j) a[j] += b2f((unsigned short)u[j]);
  }
  float inv = (end > beg) ? 1.f / (float)(end - beg) : 0.f;
  short8 qv = *(const short8*)(Pb + (size_t)node * 2 * C + C + lane * 8);
  float4 bv0 = *(const float4*)(bl + (size_t)it * C + lane * 8);
  float4 bv1 = *(const float4*)(bl + (size_t)it * C + lane * 8 + 4);
  float bb[8] = {bv0.x, bv0.y, bv0.z, bv0.w, bv1.x, bv1.y, bv1.z, bv1.w};
  short8 o;
#pragma unroll
  for (int j = 0; j < 8; ++j)
    o[j] = (short)f2b(fmaxf(a[j] * inv + b2f((unsigned short)qv[j]) + bb[j], 0.f));
  *hp = o;
}

// ---------------- combine L3: out(+)= sum_it w[it]*(mean_gather(P3) + bl3 + Q3) ----------------
// one wave per node (64 lanes x 8 cols = 512); 2 nodes per 128-thread block;
// fin!=0: fused row L2-normalize via wave-local shuffle reduce (no LDS/barrier)
__global__ __launch_bounds__(128) void combine3_k(const unsigned short* __restrict__ PQ,
                                                  const float* __restrict__ bl3,
                                                  const float* __restrict__ wsm,
                                                  const int* __restrict__ rowptr,
                                                  const int* __restrict__ colidx,
                                                  float* __restrict__ out, int it0, int nb,
                                                  int acc, int fin) {
  int wid = threadIdx.x >> 6;
  int lane = threadIdx.x & 63;
  int node = blockIdx.x * 2 + wid;
  if (node >= N_NODES) return;
  float s[8];
#pragma unroll
  for (int j = 0; j < 8; ++j) s[j] = 0.f;
  for (int itl = 0; itl < nb; ++itl) {
    int it = it0 + itl;
    const unsigned short* Pb = PQ + (size_t)itl * MPAD * 1024;
    const int* rp = rowptr + (size_t)it * (N_NODES + 1);
    const int* ci = colidx + (size_t)it * N_EDGES;
    int beg = rp[node], end = rp[node + 1];
    float a[8];
#pragma unroll
    for (int j = 0; j < 8; ++j) a[j] = 0.f;
    for (int e = beg; e < end; ++e) {
      int src = ci[e];
      short8 u = *(const short8*)(Pb + (size_t)src * 1024 + lane * 8);
#pragma unroll
      for (int j = 0; j < 8; ++j) a[j] += b2f((unsigned short)u[j]);
    }
    float inv = (end > beg) ? 1.f / (float)(end - beg) : 0.f;
    short8 qv = *(const short8*)(Pb + (size_t)node * 1024 + 512 + lane * 8);
    float4 bv0 = *(const float4*)(bl3 + (size_t)it * OUT_C + lane * 8);
    float4 bv1 = *(const float4*)(bl3 + (size_t)it * OUT_C + lane * 8 + 4);
    float bb[8] = {bv0.x, bv0.y, bv0.z, bv0.w, bv1.x, bv1.y, bv1.z, bv1.w};
    float w = wsm[it];
#pragma unroll
    for (int j = 0; j < 8; ++j)
      s[j] += w * (a[j] * inv + b2f((unsigned short)qv[j]) + bb[j]);
  }
  float* op = out + (size_t)node * OUT_C + lane * 8;
  if (acc) {
    float4 c0 = *(const float4*)op;
    float4 c1 = *(const float4*)(op + 4);
    s[0] += c0.x; s[1] += c0.y; s[2] += c0.z; s[3] += c0.w;
    s[4] += c1.x; s[5] += c1.y; s[6] += c1.z; s[7] += c1.w;
  }
  if (fin) {
    float ss = 0.f;
#pragma unroll
    for (int j = 0; j < 8; ++j) ss += s[j] * s[j];
    for (int o2 = 32; o2 > 0; o2 >>= 1) ss += __shfl_down(ss, o2);
    ss = __shfl(ss, 0);
    float inv = 1.f / fmaxf(sqrtf(ss), 1e-12f);
#pragma unroll
    for (int j = 0; j < 8; ++j) s[j] *= inv;
  }
  float4 o0 = {s[0], s[1], s[2], s[3]};
  float4 o1 = {s[4], s[5], s[6], s[7]};
  *(float4*)op = o0;
  *(float4*)(op + 4) = o1;
}

// ---------------- launch ----------------
extern "C" void kernel_launch(void* const* d_in, const int* in_sizes, int n_in,
                              void* d_out, int out_size, void* d_ws, size_t ws_size,
                              hipStream_t stream) {
  const float* x    = (const float*)d_in[0];
  const int*   edges = (const int*)d_in[1];
  const float* Wl1 = (const float*)d_in[2];
  const float* bl1 = (const float*)d_in[3];
  const float* Wr1 = (const float*)d_in[4];
  const float* Wl2 = (const float*)d_in[5];
  const float* bl2 = (const float*)d_in[6];
  const float* Wr2 = (const float*)d_in[7];
  const float* Wl3 = (const float*)d_in[8];
  const float* bl3 = (const float*)d_in[9];
  const float* Wr3 = (const float*)d_in[10];
  const float* attn = (const float*)d_in[11];
  float* out = (float*)d_out;

  char* ws = (char*)d_ws;
  size_t off = 0;
  auto alloc = [&](size_t bytes) -> char* {
    char* p = ws + off;
    off = (off + bytes + 255) & ~(size_t)255;
    return p;
  };
  float* wsm   = (float*)alloc(N_TYPES * 4);
  int* deg     = (int*)alloc((size_t)N_TYPES * N_NODES * 4);
  int* rowptr  = (int*)alloc((size_t)N_TYPES * (N_NODES + 1) * 4);
  int* cursor  = (int*)alloc((size_t)N_TYPES * N_NODES * 4);
  int* colidx  = (int*)alloc((size_t)N_TYPES * N_EDGES * 4);
  unsigned short* xb    = (unsigned short*)alloc((size_t)MPAD * IN_C * 2);
  unsigned short* wcat1 = (unsigned short*)alloc((size_t)N_TYPES * 2 * HID_C * IN_C * 2);
  unsigned short* wcat2 = (unsigned short*)alloc((size_t)N_TYPES * 2 * HID_C * HID_C * 2);
  unsigned short* wcat3 = (unsigned short*)alloc((size_t)N_TYPES * 2 * OUT_C * HID_C * 2);
  size_t persist = off;

  // pick largest type-batch nb that fits: need = persist + nb*(PQ 2C + h C) slabs
  const size_t pqSlab = (size_t)MPAD * 2 * HID_C * 2;   // 82.9 MB
  const size_t hSlab  = (size_t)MPAD * HID_C * 2;       // 41.4 MB
  int nb = 1;
  for (int c = N_TYPES; c >= 1; --c) {
    size_t need = persist + (size_t)c * (pqSlab + hSlab) + 4096;
    if (need <= ws_size) { nb = c; break; }
  }
  unsigned short* PQ   = (unsigned short*)alloc((size_t)nb * pqSlab);
  unsigned short* hbuf = (unsigned short*)alloc((size_t)nb * hSlab);

  // prep
  softmax5_k<<<1, 64, 0, stream>>>(attn, wsm);
  zero_int_k<<<(N_TYPES * N_NODES + 255) / 256, 256, 0, stream>>>(deg, N_TYPES * N_NODES);
  hist_k<<<(N_TYPES * N_EDGES + 255) / 256, 256, 0, stream>>>(edges, deg);
  scan_k<<<N_TYPES, 256, 0, stream>>>(deg, rowptr, cursor);
  scatter_k<<<(N_TYPES * N_EDGES + 255) / 256, 256, 0, stream>>>(edges, cursor, colidx);

  cvt_x_k<<<((size_t)MPAD * IN_C / 4 + 255) / 256, 256, 0, stream>>>(x, xb);
  {
    int t1 = N_TYPES * HID_C * (IN_C / 4);
    cvt_wcat_k<<<(t1 + 255) / 256, 256, 0, stream>>>(Wl1, wcat1, HID_C, IN_C / 4, 0);
    cvt_wcat_k<<<(t1 + 255) / 256, 256, 0, stream>>>(Wr1, wcat1, HID_C, IN_C / 4, HID_C);
    int t2 = N_TYPES * HID_C * (HID_C / 4);
    cvt_wcat_k<<<(t2 + 255) / 256, 256, 0, stream>>>(Wl2, wcat2, HID_C, HID_C / 4, 0);
    cvt_wcat_k<<<(t2 + 255) / 256, 256, 0, stream>>>(Wr2, wcat2, HID_C, HID_C / 4, HID_C);
    int t3 = N_TYPES * OUT_C * (HID_C / 4);
    cvt_wcat_k<<<(t3 + 255) / 256, 256, 0, stream>>>(Wl3, wcat3, OUT_C, HID_C / 4, 0);
    cvt_wcat_k<<<(t3 + 255) / 256, 256, 0, stream>>>(Wr3, wcat3, OUT_C, HID_C / 4, OUT_C);
  }

  const int MT = MPAD / 128;
  for (int g0 = 0; g0 < N_TYPES; g0 += nb) {
    int nbg = (N_TYPES - g0 < nb) ? (N_TYPES - g0) : nb;
    int fin = (g0 + nbg >= N_TYPES) ? 1 : 0;
    // layer 1: PQ = x @ [Wl1;Wr1]^T   (A shared across types: stride 0)
    gemm_k<2 * HID_C, IN_C><<<nbg * MT * (2 * HID_C / 256), 512, 0, stream>>>(
        xb, 0, wcat1 + (size_t)g0 * 2 * HID_C * IN_C, PQ);
    combine12_k<<<nbg * (MPAD / 2), 256, 0, stream>>>(PQ, hbuf, bl1, rowptr, colidx, g0);
    // layer 2: PQ = h1 @ [Wl2;Wr2]^T
    gemm_k<2 * HID_C, HID_C><<<nbg * MT * (2 * HID_C / 256), 512, 0, stream>>>(
        hbuf, hSlab / 2, wcat2 + (size_t)g0 * 2 * HID_C * HID_C, PQ);
    combine12_k<<<nbg * (MPAD / 2), 256, 0, stream>>>(PQ, hbuf, bl2, rowptr, colidx, g0);
    // layer 3: PQ3 = h2 @ [Wl3;Wr3]^T  (N=1024)
    gemm_k<2 * OUT_C, HID_C><<<nbg * MT * (2 * OUT_C / 256), 512, 0, stream>>>(
        hbuf, hSlab / 2, wcat3 + (size_t)g0 * 2 * OUT_C * HID_C, PQ);
    combine3_k<<<(N_NODES + 1) / 2, 128, 0, stream>>>(PQ, bl3, wsm, rowptr, colidx, out,
                                                      g0, nbg, (g0 > 0) ? 1 : 0, fin);
  }
}

// Round 14
// 2116.036 us; speedup vs baseline: 1.1245x; 1.1245x over previous
//
#include <hip/hip_runtime.h>
#include <hip/hip_bf16.h>
#include <stdint.h>

// ---------------- constants ----------------
#define N_NODES   20000
#define MPAD      20224          // 158*128 = 79*256
#define N_TYPES   5
#define N_EDGES   64000
#define IN_C      2048
#define HID_C     1024
#define OUT_C     512

typedef __attribute__((ext_vector_type(8))) short short8;   // 8 bf16 (4 VGPR)
typedef __attribute__((ext_vector_type(4))) float f32x4;

// ---------------- helpers ----------------
__device__ __forceinline__ unsigned short f2b(float f) {
  union { float f; uint32_t u; } c; c.f = f;
  uint32_t u = c.u;
  u += 0x7FFFu + ((u >> 16) & 1u);          // RNE
  return (unsigned short)(u >> 16);
}
__device__ __forceinline__ float b2f(unsigned short h) {
  union { uint32_t u; float f; } c; c.u = ((uint32_t)h) << 16; return c.f;
}
__device__ __forceinline__ void gload_lds16(const void* g, void* l) {
  __builtin_amdgcn_global_load_lds((__attribute__((address_space(1))) void*)g,
                                   (__attribute__((address_space(3))) void*)l,
                                   16, 0, 0);
}

// ---------------- small prep kernels ----------------
__global__ __launch_bounds__(64) void softmax5_k(const float* __restrict__ attn, float* __restrict__ w) {
  if (threadIdx.x == 0) {
    float m = attn[0];
    for (int i = 1; i < N_TYPES; ++i) m = fmaxf(m, attn[i]);
    float e[N_TYPES], s = 0.f;
    for (int i = 0; i < N_TYPES; ++i) { e[i] = expf(attn[i] - m); s += e[i]; }
    for (int i = 0; i < N_TYPES; ++i) w[i] = e[i] / s;
  }
}

__global__ __launch_bounds__(256) void zero_int_k(int* __restrict__ p, int n) {
  int i = blockIdx.x * 256 + threadIdx.x;
  if (i < n) p[i] = 0;
}

__global__ __launch_bounds__(256) void hist_k(const int* __restrict__ edges, int* __restrict__ deg) {
  int t = blockIdx.x * 256 + threadIdx.x;
  if (t < N_TYPES * N_EDGES) {
    int ty = t / N_EDGES, e = t - ty * N_EDGES;
    int dst = edges[ty * 2 * N_EDGES + N_EDGES + e];
    atomicAdd(&deg[ty * N_NODES + dst], 1);
  }
}

__global__ __launch_bounds__(256) void scan_k(const int* __restrict__ deg, int* __restrict__ rowptr,
                                              int* __restrict__ cursor) {
  int ty = blockIdx.x;
  const int* d = deg + ty * N_NODES;
  int* rp = rowptr + ty * (N_NODES + 1);
  int* cu = cursor + ty * N_NODES;
  __shared__ int sh[256];
  __shared__ int s_carry;
  int tid = threadIdx.x;
  if (tid == 0) s_carry = 0;
  __syncthreads();
  for (int base = 0; base < N_NODES; base += 256) {
    int i = base + tid;
    int v = (i < N_NODES) ? d[i] : 0;
    sh[tid] = v; __syncthreads();
    for (int off = 1; off < 256; off <<= 1) {
      int t2 = (tid >= off) ? sh[tid - off] : 0;
      __syncthreads();
      sh[tid] += t2;
      __syncthreads();
    }
    int incl = sh[tid];
    int c = s_carry;
    if (i < N_NODES) { rp[i] = c + incl - v; cu[i] = c + incl - v; }
    __syncthreads();
    if (tid == 255) s_carry = c + incl;
    __syncthreads();
  }
  if (tid == 0) rp[N_NODES] = s_carry;
}

__global__ __launch_bounds__(256) void scatter_k(const int* __restrict__ edges, int* __restrict__ cursor,
                                                 int* __restrict__ colidx) {
  int t = blockIdx.x * 256 + threadIdx.x;
  if (t < N_TYPES * N_EDGES) {
    int ty = t / N_EDGES, e = t - ty * N_EDGES;
    int src = edges[ty * 2 * N_EDGES + e];
    int dst = edges[ty * 2 * N_EDGES + N_EDGES + e];
    int pos = atomicAdd(&cursor[ty * N_NODES + dst], 1);
    colidx[ty * N_EDGES + pos] = src;
  }
}

// x fp32 [20000,2048] -> bf16 [20224,2048], pad rows zero
__global__ __launch_bounds__(256) void cvt_x_k(const float* __restrict__ x, unsigned short* __restrict__ xb) {
  int i = blockIdx.x * 256 + threadIdx.x;
  int row = i >> 9;
  int c4 = (i & 511) << 2;
  if (row >= MPAD) return;
  ushort4 o;
  if (row < N_NODES) {
    float4 v = *(const float4*)(x + (size_t)row * IN_C + c4);
    o.x = f2b(v.x); o.y = f2b(v.y); o.z = f2b(v.z); o.w = f2b(v.w);
  } else { o.x = 0; o.y = 0; o.z = 0; o.w = 0; }
  *(ushort4*)(xb + (size_t)row * IN_C + c4) = o;
}

// fp32 W [5][C][K] -> bf16 Wcat [5][2C][K], placed at row offset rowoff
__global__ __launch_bounds__(256) void cvt_wcat_k(const float* __restrict__ s,
                                                  unsigned short* __restrict__ d,
                                                  int C, int K4, int rowoff) {
  int i = blockIdx.x * 256 + threadIdx.x;
  int total = N_TYPES * C * K4;
  if (i >= total) return;
  int k4 = i % K4;
  int rr = (i / K4) % C;
  int it = i / (C * K4);
  float4 v = ((const float4*)s)[i];
  ushort4 o; o.x = f2b(v.x); o.y = f2b(v.y); o.z = f2b(v.z); o.w = f2b(v.w);
  ((ushort4*)d)[((size_t)it * 2 * C + rowoff + rr) * K4 + k4] = o;
}

// ---------------- GEMM: PQ[itl] = A[itl] @ Wcat[itl]^T  (128x256 tile, ring-3, 2 blocks/CU) ----
// r12 configuration: cumulative best (505 µs / MfmaUtil 47 / 0 conflicts on the nbg=3 L1).
// 8 waves (2Mx4N), per-wave 64x64, BK=32, mfma_f32_16x16x32_bf16.
// LDS: 3 ring slots x (A[128x32]=8KB + B[256x32]=16KB) = 72 KiB -> 2 blocks/CU.
// Counted-vmcnt pipeline: lookahead-2, steady vmcnt(3), one barrier per K32-tile,
// hoisted ds_reads. Closed lanes (all regressed): r7 4-barrier phase split, r8 ring-2
// drain-0, r10/r13 32x32 MFMA (conflicts / insufficient MFMA ILP).
// LDS rows 128 B, slot swizzle byte^=(((r>>1)&7)<<4): 0 bank conflicts (verified).
// Staging: LDS dest linear (global_load_lds); global SOURCE per-lane inverse-permuted.
template<int NSIZE, int KSIZE>
__global__ __launch_bounds__(512, 4) void gemm_k(
    const unsigned short* __restrict__ Abase, size_t aS,     // per-itl stride (0 = shared A)
    const unsigned short* __restrict__ Wbase,                // [itl][NSIZE][KSIZE] (group-offset)
    unsigned short* __restrict__ PQ) {                       // [itl][MPAD][NSIZE]
  constexpr int NT = KSIZE / 32;
  constexpr int MT = MPAD / 128;     // BM = 128
  constexpr int NB = NSIZE / 256;    // BN = 256
  __shared__ unsigned short As[3][4096];   // [64 LDS-rows][128 B]
  __shared__ unsigned short Bs[3][8192];   // [128 LDS-rows][128 B]
  const int tid = threadIdx.x;
  const int lane = tid & 63;
  const int wave = tid >> 6;
  const int wm = wave >> 2, wn = wave & 3;   // 2M x 4N, per-wave 64x64

  // XCD-chunked bijective swizzle (m204), column-fastest within type
  const int nwg = gridDim.x;
  const int flat = blockIdx.x;
  const int q8 = nwg >> 3, r8 = nwg & 7;
  const int xcd = flat & 7, idx = flat >> 3;
  const int wg = (xcd < r8) ? (xcd * (q8 + 1) + idx) : (r8 * (q8 + 1) + (xcd - r8) * q8 + idx);
  const int itl = wg / (MT * NB);
  const int rem = wg % (MT * NB);
  const int row0 = (rem / NB) * 128;
  const int col0 = (rem % NB) * 256;

  const unsigned short* A = Abase + (size_t)itl * aS;
  const unsigned short* W = Wbase + (size_t)itl * NSIZE * KSIZE;

  // staging lane constants (inverse of read swizzle)
  const int sR = lane >> 3;                    // LDS-row within 8-LDS-row region
  const int su = (lane & 7) ^ (sR & 7);        // swizzled 16B-slot within 128B LDS-row
  const int srow = 2 * sR + (su >> 2);         // tile-row within 16-row region
  const int selem = (su & 3) * 8;              // k element offset (16 B)

  // fragment read byte offsets
  const int fr = lane & 15, k16 = lane >> 4;
  int aoff[4], boff[4];
#pragma unroll
  for (int m = 0; m < 4; ++m) {
    int r = wm * 64 + m * 16 + fr;
    aoff[m] = (((r >> 1) << 7) + ((r & 1) << 6) + (k16 << 4)) ^ (((r >> 1) & 7) << 4);
  }
#pragma unroll
  for (int n = 0; n < 4; ++n) {
    int r = wn * 64 + n * 16 + fr;
    boff[n] = (((r >> 1) << 7) + ((r & 1) << 6) + (k16 << 4)) ^ (((r >> 1) & 7) << 4);
  }

  auto stageA = [&](int t) {           // 1 load/wave: region = wave (16 tile-rows)
    int s = t % 3; int kb = t * 32;
    gload_lds16(A + (size_t)(row0 + wave * 16 + srow) * KSIZE + kb + selem, &As[s][wave * 512]);
  };
  auto stageB = [&](int t) {           // 2 loads/wave: regions wave, wave+8
    int s = t % 3; int kb = t * 32;
#pragma unroll
    for (int j = 0; j < 2; ++j) {
      int reg = wave + 8 * j;
      gload_lds16(W + (size_t)(col0 + reg * 16 + srow) * KSIZE + kb + selem, &Bs[s][reg * 512]);
    }
  };

  f32x4 acc[4][4];
#pragma unroll
  for (int m = 0; m < 4; ++m)
#pragma unroll
    for (int n = 0; n < 4; ++n) acc[m][n] = (f32x4)(0.f);

  // prologue: tiles 0,1 staged (6 loads/wave in flight)
  stageA(0); stageB(0);
  stageA(1); stageB(1);

  for (int t = 0; t < NT; ++t) {
    if (t < NT - 1) asm volatile("s_waitcnt vmcnt(3)" ::: "memory");
    else            asm volatile("s_waitcnt vmcnt(0)" ::: "memory");
    __builtin_amdgcn_s_barrier();
    __builtin_amdgcn_sched_barrier(0);
    const int slot = t % 3;
    const char* pa = (const char*)As[slot];
    const char* pb = (const char*)Bs[slot];
    // cluster 1: A frags + B lo; stage A(t+2); 8 MFMA
    short8 af[4], bf[2];
#pragma unroll
    for (int m = 0; m < 4; ++m) af[m] = *(const short8*)(pa + aoff[m]);
#pragma unroll
    for (int n = 0; n < 2; ++n) bf[n] = *(const short8*)(pb + boff[n]);
    if (t + 2 < NT) stageA(t + 2);
    __builtin_amdgcn_s_setprio(1);
#pragma unroll
    for (int m = 0; m < 4; ++m)
#pragma unroll
      for (int n = 0; n < 2; ++n)
        acc[m][n] = __builtin_amdgcn_mfma_f32_16x16x32_bf16(af[m], bf[n], acc[m][n], 0, 0, 0);
    __builtin_amdgcn_s_setprio(0);
    // cluster 2: B hi; stage B(t+2); 8 MFMA
    short8 bh[2];
#pragma unroll
    for (int n = 0; n < 2; ++n) bh[n] = *(const short8*)(pb + boff[n + 2]);
    if (t + 2 < NT) stageB(t + 2);
    __builtin_amdgcn_s_setprio(1);
#pragma unroll
    for (int m = 0; m < 4; ++m)
#pragma unroll
      for (int n = 0; n < 2; ++n)
        acc[m][n + 2] = __builtin_amdgcn_mfma_f32_16x16x32_bf16(af[m], bh[n], acc[m][n + 2], 0, 0, 0);
    __builtin_amdgcn_s_setprio(0);
  }

  // epilogue: D layout col=lane&15, row=(lane>>4)*4+reg
  const int erow = (lane >> 4) * 4;
  const int ecol = lane & 15;
  unsigned short* Op = PQ + (size_t)itl * MPAD * NSIZE;
#pragma unroll
  for (int m = 0; m < 4; ++m) {
#pragma unroll
    for (int n = 0; n < 4; ++n) {
      int gcol = col0 + wn * 64 + n * 16 + ecol;
#pragma unroll
      for (int r = 0; r < 4; ++r) {
        int grow = row0 + wm * 64 + m * 16 + erow + r;
        Op[(size_t)grow * NSIZE + gcol] = f2b(acc[m][n][r]);
      }
    }
  }
}

// ---------------- combine L1/L2: h' = relu(mean_gather(P) + bl + Q); pad rows zeroed ----------------
// 16 B/lane (short8); 2 nodes per 256-thread block (128 lanes x 16B = full 1024-col row)
__global__ __launch_bounds__(256) void combine12_k(const unsigned short* __restrict__ PQ,
                                                   unsigned short* __restrict__ Hn,
                                                   const float* __restrict__ bl,
                                                   const int* __restrict__ rowptr,
                                                   const int* __restrict__ colidx, int it0) {
  constexpr int C = HID_C;
  constexpr int HP = MPAD / 2;
  int itl = blockIdx.x / HP;
  int pair = blockIdx.x % HP;
  int half = threadIdx.x >> 7;              // 0/1: which node of the pair
  int lane = threadIdx.x & 127;             // 128 lanes x 8 bf16 = 1024 cols
  int node = pair * 2 + half;
  int it = it0 + itl;
  short8* hp = (short8*)(Hn + ((size_t)itl * MPAD + node) * C + lane * 8);
  if (node >= N_NODES) { short8 z = (short8)0; *hp = z; return; }
  const unsigned short* Pb = PQ + (size_t)itl * MPAD * 2 * C;
  const int* rp = rowptr + (size_t)it * (N_NODES + 1);
  const int* ci = colidx + (size_t)it * N_EDGES;
  int beg = rp[node], end = rp[node + 1];
  float a[8];
#pragma unroll
  for (int j = 0; j < 8; ++j) a[j] = 0.f;
  for (int e = beg; e < end; ++e) {
    int src = ci[e];
    short8 u = *(const short8*)(Pb + (size_t)src * 2 * C + lane * 8);
#pragma unroll
    for (int j = 0; j < 8; ++j) a[j] += b2f((unsigned short)u[j]);
  }
  float inv = (end > beg) ? 1.f / (float)(end - beg) : 0.f;
  short8 qv = *(const short8*)(Pb + (size_t)node * 2 * C + C + lane * 8);
  float4 bv0 = *(const float4*)(bl + (size_t)it * C + lane * 8);
  float4 bv1 = *(const float4*)(bl + (size_t)it * C + lane * 8 + 4);
  float bb[8] = {bv0.x, bv0.y, bv0.z, bv0.w, bv1.x, bv1.y, bv1.z, bv1.w};
  short8 o;
#pragma unroll
  for (int j = 0; j < 8; ++j)
    o[j] = (short)f2b(fmaxf(a[j] * inv + b2f((unsigned short)qv[j]) + bb[j], 0.f));
  *hp = o;
}

// ---------------- combine L3: out(+)= sum_it w[it]*(mean_gather(P3) + bl3 + Q3) ----------------
// one wave per node (64 lanes x 8 cols = 512); 2 nodes per 128-thread block;
// fin!=0: fused row L2-normalize via wave-local shuffle reduce (no LDS/barrier)
__global__ __launch_bounds__(128) void combine3_k(const unsigned short* __restrict__ PQ,
                                                  const float* __restrict__ bl3,
                                                  const float* __restrict__ wsm,
                                                  const int* __restrict__ rowptr,
                                                  const int* __restrict__ colidx,
                                                  float* __restrict__ out, int it0, int nb,
                                                  int acc, int fin) {
  int wid = threadIdx.x >> 6;
  int lane = threadIdx.x & 63;
  int node = blockIdx.x * 2 + wid;
  if (node >= N_NODES) return;
  float s[8];
#pragma unroll
  for (int j = 0; j < 8; ++j) s[j] = 0.f;
  for (int itl = 0; itl < nb; ++itl) {
    int it = it0 + itl;
    const unsigned short* Pb = PQ + (size_t)itl * MPAD * 1024;
    const int* rp = rowptr + (size_t)it * (N_NODES + 1);
    const int* ci = colidx + (size_t)it * N_EDGES;
    int beg = rp[node], end = rp[node + 1];
    float a[8];
#pragma unroll
    for (int j = 0; j < 8; ++j) a[j] = 0.f;
    for (int e = beg; e < end; ++e) {
      int src = ci[e];
      short8 u = *(const short8*)(Pb + (size_t)src * 1024 + lane * 8);
#pragma unroll
      for (int j = 0; j < 8; ++j) a[j] += b2f((unsigned short)u[j]);
    }
    float inv = (end > beg) ? 1.f / (float)(end - beg) : 0.f;
    short8 qv = *(const short8*)(Pb + (size_t)node * 1024 + 512 + lane * 8);
    float4 bv0 = *(const float4*)(bl3 + (size_t)it * OUT_C + lane * 8);
    float4 bv1 = *(const float4*)(bl3 + (size_t)it * OUT_C + lane * 8 + 4);
    float bb[8] = {bv0.x, bv0.y, bv0.z, bv0.w, bv1.x, bv1.y, bv1.z, bv1.w};
    float w = wsm[it];
#pragma unroll
    for (int j = 0; j < 8; ++j)
      s[j] += w * (a[j] * inv + b2f((unsigned short)qv[j]) + bb[j]);
  }
  float* op = out + (size_t)node * OUT_C + lane * 8;
  if (acc) {
    float4 c0 = *(const float4*)op;
    float4 c1 = *(const float4*)(op + 4);
    s[0] += c0.x; s[1] += c0.y; s[2] += c0.z; s[3] += c0.w;
    s[4] += c1.x; s[5] += c1.y; s[6] += c1.z; s[7] += c1.w;
  }
  if (fin) {
    float ss = 0.f;
#pragma unroll
    for (int j = 0; j < 8; ++j) ss += s[j] * s[j];
    for (int o2 = 32; o2 > 0; o2 >>= 1) ss += __shfl_down(ss, o2);
    ss = __shfl(ss, 0);
    float inv = 1.f / fmaxf(sqrtf(ss), 1e-12f);
#pragma unroll
    for (int j = 0; j < 8; ++j) s[j] *= inv;
  }
  float4 o0 = {s[0], s[1], s[2], s[3]};
  float4 o1 = {s[4], s[5], s[6], s[7]};
  *(float4*)op = o0;
  *(float4*)(op + 4) = o1;
}

// ---------------- launch ----------------
extern "C" void kernel_launch(void* const* d_in, const int* in_sizes, int n_in,
                              void* d_out, int out_size, void* d_ws, size_t ws_size,
                              hipStream_t stream) {
  const float* x    = (const float*)d_in[0];
  const int*   edges = (const int*)d_in[1];
  const float* Wl1 = (const float*)d_in[2];
  const float* bl1 = (const float*)d_in[3];
  const float* Wr1 = (const float*)d_in[4];
  const float* Wl2 = (const float*)d_in[5];
  const float* bl2 = (const float*)d_in[6];
  const float* Wr2 = (const float*)d_in[7];
  const float* Wl3 = (const float*)d_in[8];
  const float* bl3 = (const float*)d_in[9];
  const float* Wr3 = (const float*)d_in[10];
  const float* attn = (const float*)d_in[11];
  float* out = (float*)d_out;

  char* ws = (char*)d_ws;
  size_t off = 0;
  auto alloc = [&](size_t bytes) -> char* {
    char* p = ws + off;
    off = (off + bytes + 255) & ~(size_t)255;
    return p;
  };
  float* wsm   = (float*)alloc(N_TYPES * 4);
  int* deg     = (int*)alloc((size_t)N_TYPES * N_NODES * 4);
  int* rowptr  = (int*)alloc((size_t)N_TYPES * (N_NODES + 1) * 4);
  int* cursor  = (int*)alloc((size_t)N_TYPES * N_NODES * 4);
  int* colidx  = (int*)alloc((size_t)N_TYPES * N_EDGES * 4);
  unsigned short* xb    = (unsigned short*)alloc((size_t)MPAD * IN_C * 2);
  unsigned short* wcat1 = (unsigned short*)alloc((size_t)N_TYPES * 2 * HID_C * IN_C * 2);
  unsigned short* wcat2 = (unsigned short*)alloc((size_t)N_TYPES * 2 * HID_C * HID_C * 2);
  unsigned short* wcat3 = (unsigned short*)alloc((size_t)N_TYPES * 2 * OUT_C * HID_C * 2);
  size_t persist = off;

  // pick largest type-batch nb that fits: need = persist + nb*(PQ 2C + h C) slabs
  const size_t pqSlab = (size_t)MPAD * 2 * HID_C * 2;   // 82.9 MB
  const size_t hSlab  = (size_t)MPAD * HID_C * 2;       // 41.4 MB
  int nb = 1;
  for (int c = N_TYPES; c >= 1; --c) {
    size_t need = persist + (size_t)c * (pqSlab + hSlab) + 4096;
    if (need <= ws_size) { nb = c; break; }
  }
  unsigned short* PQ   = (unsigned short*)alloc((size_t)nb * pqSlab);
  unsigned short* hbuf = (unsigned short*)alloc((size_t)nb * hSlab);

  // prep
  softmax5_k<<<1, 64, 0, stream>>>(attn, wsm);
  zero_int_k<<<(N_TYPES * N_NODES + 255) / 256, 256, 0, stream>>>(deg, N_TYPES * N_NODES);
  hist_k<<<(N_TYPES * N_EDGES + 255) / 256, 256, 0, stream>>>(edges, deg);
  scan_k<<<N_TYPES, 256, 0, stream>>>(deg, rowptr, cursor);
  scatter_k<<<(N_TYPES * N_EDGES + 255) / 256, 256, 0, stream>>>(edges, cursor, colidx);

  cvt_x_k<<<((size_t)MPAD * IN_C / 4 + 255) / 256, 256, 0, stream>>>(x, xb);
  {
    int t1 = N_TYPES * HID_C * (IN_C / 4);
    cvt_wcat_k<<<(t1 + 255) / 256, 256, 0, stream>>>(Wl1, wcat1, HID_C, IN_C / 4, 0);
    cvt_wcat_k<<<(t1 + 255) / 256, 256, 0, stream>>>(Wr1, wcat1, HID_C, IN_C / 4, HID_C);
    int t2 = N_TYPES * HID_C * (HID_C / 4);
    cvt_wcat_k<<<(t2 + 255) / 256, 256, 0, stream>>>(Wl2, wcat2, HID_C, HID_C / 4, 0);
    cvt_wcat_k<<<(t2 + 255) / 256, 256, 0, stream>>>(Wr2, wcat2, HID_C, HID_C / 4, HID_C);
    int t3 = N_TYPES * OUT_C * (HID_C / 4);
    cvt_wcat_k<<<(t3 + 255) / 256, 256, 0, stream>>>(Wl3, wcat3, OUT_C, HID_C / 4, 0);
    cvt_wcat_k<<<(t3 + 255) / 256, 256, 0, stream>>>(Wr3, wcat3, OUT_C, HID_C / 4, OUT_C);
  }

  const int MT = MPAD / 128;
  for (int g0 = 0; g0 < N_TYPES; g0 += nb) {
    int nbg = (N_TYPES - g0 < nb) ? (N_TYPES - g0) : nb;
    int fin = (g0 + nbg >= N_TYPES) ? 1 : 0;
    // layer 1: PQ = x @ [Wl1;Wr1]^T   (A shared across types: stride 0)
    gemm_k<2 * HID_C, IN_C><<<nbg * MT * (2 * HID_C / 256), 512, 0, stream>>>(
        xb, 0, wcat1 + (size_t)g0 * 2 * HID_C * IN_C, PQ);
    combine12_k<<<nbg * (MPAD / 2), 256, 0, stream>>>(PQ, hbuf, bl1, rowptr, colidx, g0);
    // layer 2: PQ = h1 @ [Wl2;Wr2]^T
    gemm_k<2 * HID_C, HID_C><<<nbg * MT * (2 * HID_C / 256), 512, 0, stream>>>(
        hbuf, hSlab / 2, wcat2 + (size_t)g0 * 2 * HID_C * HID_C, PQ);
    combine12_k<<<nbg * (MPAD / 2), 256, 0, stream>>>(PQ, hbuf, bl2, rowptr, colidx, g0);
    // layer 3: PQ3 = h2 @ [Wl3;Wr3]^T  (N=1024)
    gemm_k<2 * OUT_C, HID_C><<<nbg * MT * (2 * OUT_C / 256), 512, 0, stream>>>(
        hbuf, hSlab / 2, wcat3 + (size_t)g0 * 2 * OUT_C * HID_C, PQ);
    combine3_k<<<(N_NODES + 1) / 2, 128, 0, stream>>>(PQ, bl3, wsm, rowptr, colidx, out,
                                                      g0, nbg, (g0 > 0) ? 1 : 0, fin);
  }
}